// Round 7
// baseline (211.204 us; speedup 1.0000x reference)
//
#include <hip/hip_runtime.h>

#define B_ 4
#define S_ 2048
#define D_ 512
#define H_ 8

typedef __attribute__((ext_vector_type(8))) __bf16 bf16x8;
typedef __attribute__((ext_vector_type(4))) float f32x4;

#define NEGBIG  -1.442695040e9f          // -1e9 * log2(e): masks live in exp2 domain
#define QSCALE  0.18033688011112042f     // 0.125 * log2(e) folded into Q

// pack two floats -> two bf16 (RNE-ish, ties-up): 2 adds + 1 v_perm
__device__ __forceinline__ unsigned pack_rn(float a, float b) {
    union { float f; unsigned u; } ua, ub; ua.f = a; ub.f = b;
    return __builtin_amdgcn_perm(ub.u + 0x8000u, ua.u + 0x8000u, 0x07060302u);
}

// async global->LDS, 16B per lane. LDS dest = wave-uniform base + lane*16.
__device__ __forceinline__ void gl16(const void* g, void* l) {
    __builtin_amdgcn_global_load_lds(
        (const __attribute__((address_space(1))) unsigned int*)g,
        (__attribute__((address_space(3))) unsigned int*)l, 16, 0, 0);
}

// ---------------------------------------------------------------------------
// Fused preprocessing (one launch) — UNCHANGED from r5/r6.
// ---------------------------------------------------------------------------
__global__ __launch_bounds__(256) void pre_all(
    const float* __restrict__ q, const float* __restrict__ v,
    const int* __restrict__ am,
    const float* __restrict__ Wq, const float* __restrict__ Wk,
    const float* __restrict__ Wv, const float* __restrict__ Wo,
    unsigned short* __restrict__ xq, unsigned short* __restrict__ xv,
    unsigned short* __restrict__ Tq, unsigned short* __restrict__ Tk,
    unsigned short* __restrict__ Tv, unsigned short* __restrict__ To,
    int* __restrict__ idxc, int* __restrict__ nvout,
    float* __restrict__ Mf, float* __restrict__ Mc)
{
    const int bid = blockIdx.x;
    const int tid = threadIdx.x;

    if (bid < 4096) {                       // ---- cast_x ----
        const int z = bid >> 11, xb = bid & 2047;
        const float* src = z ? v : q;
        unsigned short* dst = z ? xv : xq;
        int i = (xb * 256 + tid) * 8;
        float4 f0 = *(const float4*)&src[i];
        float4 f1 = *(const float4*)&src[i + 4];
        uint4 o;
        o.x = pack_rn(f0.x, f0.y); o.y = pack_rn(f0.z, f0.w);
        o.z = pack_rn(f1.x, f1.y); o.w = pack_rn(f1.z, f1.w);
        *(uint4*)&dst[i] = o;
    } else if (bid < 4352) {                // ---- cast_wt ----
        int r = bid - 4096;
        int z = r >> 6, rem = r & 63;
        const float* W = (z == 0) ? Wq : (z == 1) ? Wk : (z == 2) ? Wv : Wo;
        unsigned short* T = (z == 0) ? Tq : (z == 1) ? Tk : (z == 2) ? Tv : To;
        int n0 = (rem & 7) * 64, k0 = (rem >> 3) * 64;

        __shared__ float Ts[64][69];
        #pragma unroll
        for (int it = 0; it < 4; it++) {
            int lin = tid + it * 256;
            int kr = lin >> 4, c4 = (lin & 15) * 4;
            float4 vv = *(const float4*)&W[(k0 + kr) * 512 + n0 + c4];
            Ts[kr][c4 + 0] = vv.x; Ts[kr][c4 + 1] = vv.y;
            Ts[kr][c4 + 2] = vv.z; Ts[kr][c4 + 3] = vv.w;
        }
        __syncthreads();
        int n = tid >> 2, kc = tid & 3;
        unsigned p[8];
        #pragma unroll
        for (int j = 0; j < 8; j++)
            p[j] = pack_rn(Ts[kc * 16 + 2 * j][n], Ts[kc * 16 + 2 * j + 1][n]);
        unsigned short* dst = &T[(n0 + n) * 512 + k0 + kc * 16];
        *(uint4*)dst       = *(uint4*)&p[0];
        *(uint4*)(dst + 8) = *(uint4*)&p[4];
    } else {                                // ---- compact + masks ----
        const int w = tid >> 6, lane = tid & 63;   // wave w = batch w
        const int* amb = am + w * 2048;
        int m[32];
        #pragma unroll
        for (int s = 0; s < 32; s++) m[s] = amb[s * 64 + lane];  // all issued up front

        int* ib = idxc + w * 2048;
        const unsigned long long lt = (1ULL << lane) - 1ULL;
        int base = 0;
        #pragma unroll
        for (int s = 0; s < 32; s++) {
            unsigned long long bal = __ballot(m[s] != 0);
            if (m[s]) ib[base + __popcll(bal & lt)] = s * 64 + lane;
            base += __popcll(bal);
        }
        const int nv = base;
        for (int i = nv + lane; i < 2048; i += 64) ib[i] = 0;   // pad -> row 0
        float* mfb = Mf + w * 2048;
        float* mcb = Mc + w * 2048;
        #pragma unroll
        for (int s = 0; s < 32; s++) {
            int i = s * 64 + lane;
            mfb[i] = m[s] ? 0.f : NEGBIG;
            mcb[i] = (i < nv) ? 0.f : NEGBIG;
        }
        if (lane == 0) nvout[w] = nv;
    }
}

// ---------------------------------------------------------------------------
// QKV projection GEMM — UNCHANGED from r6 (128x64 tiles, gl16 double-buffer
// with counted vmcnt, source-side XOR swizzle, fused gather, early-exit).
// ---------------------------------------------------------------------------
__global__ __launch_bounds__(256) void proj_qkv_mfma(
    const unsigned short* __restrict__ Xq, const unsigned short* __restrict__ Xv,
    const unsigned short* __restrict__ Wtq, const unsigned short* __restrict__ Wtk,
    const unsigned short* __restrict__ Wtv,
    const float* __restrict__ bq, const float* __restrict__ bk,
    const float* __restrict__ bv,
    const int* __restrict__ idxc, const int* __restrict__ nv1,
    unsigned short* __restrict__ Qb, unsigned short* __restrict__ Kb,
    unsigned short* __restrict__ VtG)
{
    const int z = blockIdx.z;
    const unsigned short* A  = (z == 0) ? Wtq : (z == 1) ? Wtk : Xv;
    const unsigned short* Bm = (z == 0) ? Xq  : (z == 1) ? Xv  : Wtv;
    const float* bias        = (z == 0) ? bq  : (z == 1) ? bk  : bv;
    const int lin0 = blockIdx.y * 128 + blockIdx.x;       // 0..511
    const int m0 = (z < 2) ? blockIdx.y * 128 : (lin0 >> 3) * 128;
    const int n0 = (z < 2) ? blockIdx.x * 64  : (lin0 & 7) * 64;

    // early-exit for blocks entirely in the dead compacted region
    if (z == 1) {
        int bb = n0 >> 11, cap = (nv1[bb] + 63) & ~63;
        if (cap < 64) cap = 64;
        if ((n0 & 2047) >= cap) return;
    }
    if (z == 2) {
        int bb = m0 >> 11, cap = (nv1[bb] + 63) & ~63;
        if (cap < 64) cap = 64;
        if ((m0 & 2047) >= cap) return;
    }

    const int tid = threadIdx.x;
    const int w = tid >> 6, lane = tid & 63;
    const int l15 = lane & 15, quad = lane >> 4;
    const int wm = (w >> 1) * 64, wn = (w & 1) * 32;

    __shared__ unsigned short As[2][128 * 64];
    __shared__ unsigned short Bs[2][64 * 64];

    // staging: srw = tid>>3 covers rows {is*32+srw}; source chunk pre-swizzled.
    const int srw  = tid >> 3;                       // 0..31
    const int csrc = (tid & 7) ^ (srw & 7);
    const unsigned short* aS[4];
    const unsigned short* bS[2];
    #pragma unroll
    for (int is = 0; is < 4; is++) {
        int ra = m0 + is * 32 + srw;
        long sa = ra;
        if (z == 2) { int bb = ra >> 11; sa = (long)bb * 2048 + idxc[bb * 2048 + (ra & 2047)]; }
        aS[is] = A + sa * 512 + csrc * 8;
    }
    #pragma unroll
    for (int is = 0; is < 2; is++) {
        int rb = n0 + is * 32 + srw;
        long sb = rb;
        if (z == 1) { int bb = rb >> 11; sb = (long)bb * 2048 + idxc[bb * 2048 + (rb & 2047)]; }
        bS[is] = Bm + sb * 512 + csrc * 8;
    }

    const int koff0 = ((quad    ) ^ (l15 & 7)) * 8;  // undo swizzle on read
    const int koff1 = ((quad + 4) ^ (l15 & 7)) * 8;

    f32x4 acc[4][2];
    #pragma unroll
    for (int i = 0; i < 4; i++)
        #pragma unroll
        for (int j = 0; j < 2; j++) acc[i][j] = (f32x4){0.f, 0.f, 0.f, 0.f};

    // ---- double-buffered K loop: 8 chunks of 64 ----
    #define STAGE_Q(buf, k0)                                        \
        do {                                                        \
            _Pragma("unroll")                                       \
            for (int is = 0; is < 4; is++)                          \
                gl16(aS[is] + (k0), &As[buf][is * 2048 + w * 512]); \
            _Pragma("unroll")                                       \
            for (int is = 0; is < 2; is++)                          \
                gl16(bS[is] + (k0), &Bs[buf][is * 2048 + w * 512]); \
        } while (0)

    STAGE_Q(0, 0);
    for (int k = 0; k < 8; k++) {
        const int cur = k & 1;
        if (k < 7) {
            STAGE_Q(cur ^ 1, (k + 1) * 64);
            asm volatile("s_waitcnt vmcnt(6)" ::: "memory");
        } else {
            asm volatile("s_waitcnt vmcnt(0)" ::: "memory");
        }
        asm volatile("s_barrier" ::: "memory");
        #pragma unroll
        for (int kc = 0; kc < 2; kc++) {
            const int ko = kc ? koff1 : koff0;
            bf16x8 a[4], bb[2];
            #pragma unroll
            for (int i = 0; i < 4; i++)
                a[i] = *(const bf16x8*)&As[cur][(wm + 16 * i + l15) * 64 + ko];
            #pragma unroll
            for (int j = 0; j < 2; j++)
                bb[j] = *(const bf16x8*)&Bs[cur][(wn + 16 * j + l15) * 64 + ko];
            #pragma unroll
            for (int i = 0; i < 4; i++)
                #pragma unroll
                for (int j = 0; j < 2; j++)
                    acc[i][j] = __builtin_amdgcn_mfma_f32_16x16x32_bf16(a[i], bb[j], acc[i][j], 0, 0, 0);
        }
        asm volatile("s_barrier" ::: "memory");
    }
    #undef STAGE_Q

    if (z == 2) {
        // V: cols = feature, rows = compacted s. ushort4 along s into (bh,d,i).
        #pragma unroll
        for (int j = 0; j < 2; j++) {
            int N = n0 + wn + 16 * j + l15;
            float bv_ = bias[N];
            int h = N >> 6, d = N & 63;
            #pragma unroll
            for (int i = 0; i < 4; i++) {
                int Mb = m0 + wm + 16 * i + quad * 4;
                int b = Mb >> 11, s = Mb & 2047;
                uint2 o;
                o.x = pack_rn(acc[i][j][0] + bv_, acc[i][j][1] + bv_);
                o.y = pack_rn(acc[i][j][2] + bv_, acc[i][j][3] + bv_);
                *(uint2*)&VtG[((b * H_ + h) * 64 + d) * 2048 + s] = o;
            }
        }
    } else {
        // Q/K: cols = s (K: compacted), rows = feature. ushort4 along d.
        unsigned short* dst = (z == 0) ? Qb : Kb;
        const float scale = (z == 0) ? QSCALE : 1.0f;
        #pragma unroll
        for (int j = 0; j < 2; j++) {
            int sg = n0 + wn + 16 * j + l15;
            int b = sg >> 11, s = sg & 2047;
            #pragma unroll
            for (int i = 0; i < 4; i++) {
                int F = m0 + wm + 16 * i + quad * 4;
                int h = F >> 6, d = F & 63;
                float4 b4 = *(const float4*)&bias[F];
                uint2 o;
                o.x = pack_rn((acc[i][j][0] + b4.x) * scale, (acc[i][j][1] + b4.y) * scale);
                o.y = pack_rn((acc[i][j][2] + b4.z) * scale, (acc[i][j][3] + b4.w) * scale);
                *(uint2*)&dst[((b * H_ + h) * 2048 + s) * 64 + d] = o;
            }
        }
    }
}

// ---------------------------------------------------------------------------
// MFMA flash attention over COMPACTED keys. r4-verified math, but q-tile 64
// (was 128): grid 1024 = 4 blocks/CU (was 2 — GRID-capped, not resource-
// capped: VGPR 80 / LDS 24KB allow 4+). Each wave owns 16 q-rows (was 32);
// 4 waves/block unchanged -> no wider barrier convoy; per-block Ks private.
// Total cycles +~20% (fixed per-tile costs amortize over half the MFMA) but
// 2x parallelism and independent co-resident blocks cross-fill the serial
// softmax <-> MFMA phases. Per-q-row arithmetic is IDENTICAL (same key
// order, same rescale sequence) -> bit-identical output expected.
// ---------------------------------------------------------------------------
__global__ __launch_bounds__(256, 4) void flash_mfma(
    const unsigned short* __restrict__ Qg, const unsigned short* __restrict__ Kg,
    const unsigned short* __restrict__ VtG, const float* __restrict__ Mf,
    const float* __restrict__ Mc, const int* __restrict__ nvalid,
    unsigned short* __restrict__ ctxB)
{
    const int bid = blockIdx.x;                  // 0..1023
    const int xcd = bid & 7, idx = bid >> 3;     // XCD x owns bh 4x..4x+3
    const int bh = xcd * 4 + (idx & 3);
    const int q0 = (idx >> 2) * 64;              // 32 q-tiles of 64
    const int b = bh >> 3, h = bh & 7;

    const int tid = threadIdx.x;
    const int w = tid >> 6, lane = tid & 63;
    const int l15 = lane & 15, quad = lane >> 4;
    const int swz = l15 & 7;

    __shared__ unsigned short Ks[2][64 * 64];    // pad-free, XOR-chunk-swizzled
    __shared__ unsigned short Ps[4][16 * 64];    // per-wave P, same swizzle
    unsigned short* pw = &Ps[w][0];

    const int nv = nvalid[b];
    int ntiles = (nv + 63) >> 6;
    if (ntiles < 1) ntiles = 1;

    const float* mfb = Mf + b * 2048;
    const float* mcp = Mc + b * 2048 + quad * 4;

    // Q fragments (B-operand) + query mask: wave w owns q rows q0+w*16+l15
    const int qrow = q0 + w * 16 + l15;
    bf16x8 qf0, qf1;
    {
        const unsigned short* p = &Qg[((long)bh * 2048 + qrow) * 64 + quad * 8];
        qf0 = *(const bf16x8*)p;
        qf1 = *(const bf16x8*)(p + 32);
    }
    const float mq = mfb[qrow];

    // V row pointers (bh,d,i layout)
    const unsigned short* vp[4];
    #pragma unroll
    for (int i = 0; i < 4; i++)
        vp[i] = VtG + ((long)bh * 64 + i * 16 + l15) * 2048 + quad * 8;

    // K staging: thread -> (row = tid>>2, chunks (tid&3)*2, +1) of 64x64 tile
    const int srow = tid >> 2;
    const int sch  = (tid & 3) * 2;
    const unsigned short* kgb = Kg + (long)bh * 2048 * 64;
    const int sw0 = srow * 64 + ((sch    ) ^ (srow & 7)) * 8;
    const int sw1 = srow * 64 + ((sch + 1) ^ (srow & 7)) * 8;

    // preamble: stage tile 0 into Ks[0]
    {
        uint4 a = *(const uint4*)&kgb[srow * 64 + sch * 8];
        uint4 c = *(const uint4*)&kgb[srow * 64 + sch * 8 + 8];
        *(uint4*)&Ks[0][sw0] = a;
        *(uint4*)&Ks[0][sw1] = c;
    }

    // swizzled fragment-read chunk offsets (kc=0 -> chunk quad, kc=1 -> 4+quad)
    const int koff0 = ((quad    ) ^ swz) * 8;
    const int koff1 = ((quad + 4) ^ swz) * 8;

    f32x4 accO[4];
    #pragma unroll
    for (int dt = 0; dt < 4; dt++) accO[dt] = (f32x4){0.f, 0.f, 0.f, 0.f};
    float mi = -3.0e38f;
    float li = 0.f;

    __syncthreads();

    for (int t = 0; t < ntiles; t++) {
        const int kt = t * 64;
        const int ktn = (t + 1 < ntiles) ? kt + 64 : kt;
        const int cur = t & 1, nxt = cur ^ 1;

        // [A] issue global loads: V frags + key-mask for THIS tile, K for NEXT
        bf16x8 vf[4][2];
        #pragma unroll
        for (int dt = 0; dt < 4; dt++) {
            vf[dt][0] = *(const bf16x8*)(vp[dt] + kt);
            vf[dt][1] = *(const bf16x8*)(vp[dt] + kt + 32);
        }
        uint4 kst0 = *(const uint4*)&kgb[(ktn + srow) * 64 + sch * 8];
        uint4 kst1 = *(const uint4*)&kgb[(ktn + srow) * 64 + sch * 8 + 8];
        f32x4 kmf[4];
        #pragma unroll
        for (int nt = 0; nt < 4; nt++)
            kmf[nt] = *(const f32x4*)(mcp + kt + nt * 16);

        // [C] K frags from LDS buf[cur] (swizzled); QK: S^T (rows=key, cols=q)
        bf16x8 kf[4][2];
        #pragma unroll
        for (int nt = 0; nt < 4; nt++) {
            kf[nt][0] = *(const bf16x8*)&Ks[cur][(nt * 16 + l15) * 64 + koff0];
            kf[nt][1] = *(const bf16x8*)&Ks[cur][(nt * 16 + l15) * 64 + koff1];
        }
        f32x4 sc[4];
        #pragma unroll
        for (int nt = 0; nt < 4; nt++) {
            f32x4 c = kmf[nt];                   // masks as C-init: exact
            c[0] += mq; c[1] += mq; c[2] += mq; c[3] += mq;
            sc[nt] = c;
        }
        __builtin_amdgcn_s_setprio(1);
        #pragma unroll
        for (int nt = 0; nt < 4; nt++) {
            sc[nt] = __builtin_amdgcn_mfma_f32_16x16x32_bf16(kf[nt][0], qf0, sc[nt], 0, 0, 0);
            sc[nt] = __builtin_amdgcn_mfma_f32_16x16x32_bf16(kf[nt][1], qf1, sc[nt], 0, 0, 0);
        }
        __builtin_amdgcn_s_setprio(0);

        // [D] online softmax (reduce over keys = in-lane + quad shfls)
        {
            float mloc = fmaxf(fmaxf(sc[0][0], sc[0][1]), fmaxf(sc[0][2], sc[0][3]));
            #pragma unroll
            for (int nt = 1; nt < 4; nt++)
                mloc = fmaxf(mloc, fmaxf(fmaxf(sc[nt][0], sc[nt][1]),
                                         fmaxf(sc[nt][2], sc[nt][3])));
            mloc = fmaxf(mloc, __shfl_xor(mloc, 16));
            mloc = fmaxf(mloc, __shfl_xor(mloc, 32));

            float mn = mi;
            if (!__all(mloc <= mn + 4.f)) {      // defer-max: P bounded by 2^4
                float mo = mn;
                mn = fmaxf(mo, mloc);
                float alpha = __builtin_amdgcn_exp2f(mo - mn);
                li *= alpha;
                #pragma unroll
                for (int dt = 0; dt < 4; dt++) {
                    accO[dt][0] *= alpha; accO[dt][1] *= alpha;
                    accO[dt][2] *= alpha; accO[dt][3] *= alpha;
                }
                mi = mn;
            }

            float ps = 0.f;
            const int prbase = l15 * 64;
            #pragma unroll
            for (int nt = 0; nt < 4; nt++) {
                float p0 = __builtin_amdgcn_exp2f(sc[nt][0] - mn);
                float p1 = __builtin_amdgcn_exp2f(sc[nt][1] - mn);
                float p2 = __builtin_amdgcn_exp2f(sc[nt][2] - mn);
                float p3 = __builtin_amdgcn_exp2f(sc[nt][3] - mn);
                ps += (p0 + p1) + (p2 + p3);
                // keys nt*16+quad*4..+3 -> chunk 2nt+(quad>>1), sub (quad&1)*4
                uint2 pp;
                pp.x = pack_rn(p0, p1);
                pp.y = pack_rn(p2, p3);
                *(uint2*)&pw[prbase + ((2 * nt + (quad >> 1)) ^ swz) * 8 + (quad & 1) * 4] = pp;
            }
            ps += __shfl_xor(ps, 16);
            ps += __shfl_xor(ps, 32);
            li += ps;
        }

        // [E] PV: O^T += Vt (A) x P^T (B)
        {
            bf16x8 pf0 = *(const bf16x8*)&pw[l15 * 64 + koff0];
            bf16x8 pf1 = *(const bf16x8*)&pw[l15 * 64 + koff1];
            __builtin_amdgcn_s_setprio(1);
            #pragma unroll
            for (int dt = 0; dt < 4; dt++) {
                accO[dt] = __builtin_amdgcn_mfma_f32_16x16x32_bf16(
                    vf[dt][0], pf0, accO[dt], 0, 0, 0);
                accO[dt] = __builtin_amdgcn_mfma_f32_16x16x32_bf16(
                    vf[dt][1], pf1, accO[dt], 0, 0, 0);
            }
            __builtin_amdgcn_s_setprio(0);
        }

        // [F] commit next K tile to LDS (waits the [A] loads), [G] barrier
        *(uint4*)&Ks[nxt][sw0] = kst0;
        *(uint4*)&Ks[nxt][sw1] = kst1;
        __syncthreads();
    }

    {
        float inv = 1.f / li;
        int obase = (b * 2048 + qrow) * 512 + h * 64 + quad * 4;
        #pragma unroll
        for (int dt = 0; dt < 4; dt++) {
            uint2 o;
            o.x = pack_rn(accO[dt][0] * inv, accO[dt][1] * inv);
            o.y = pack_rn(accO[dt][2] * inv, accO[dt][3] * inv);
            *(uint2*)&ctxB[obase + dt * 16] = o;
        }
    }
}

// ---------------------------------------------------------------------------
// Output projection — UNCHANGED from r6 (128x64 tiles, gl16 DB, counted vmcnt).
// ---------------------------------------------------------------------------
__global__ __launch_bounds__(256) void proj_out_mfma(
    const unsigned short* __restrict__ ctxB, const unsigned short* __restrict__ Wto,
    const float* __restrict__ bo, float* __restrict__ out)
{
    const int m0 = blockIdx.y * 128, n0 = blockIdx.x * 64;
    const int tid = threadIdx.x;
    const int w = tid >> 6, lane = tid & 63;
    const int l15 = lane & 15, quad = lane >> 4;
    const int wm = (w >> 1) * 64, wn = (w & 1) * 32;

    __shared__ unsigned short As[2][128 * 64];
    __shared__ unsigned short Bs[2][64 * 64];

    const int srw  = tid >> 3;
    const int csrc = (tid & 7) ^ (srw & 7);
    const unsigned short* aS[4];
    const unsigned short* bS[2];
    #pragma unroll
    for (int is = 0; is < 4; is++)
        aS[is] = Wto  + (long)(m0 + is * 32 + srw) * 512 + csrc * 8;
    #pragma unroll
    for (int is = 0; is < 2; is++)
        bS[is] = ctxB + (long)(n0 + is * 32 + srw) * 512 + csrc * 8;

    const int koff0 = ((quad    ) ^ (l15 & 7)) * 8;
    const int koff1 = ((quad + 4) ^ (l15 & 7)) * 8;

    f32x4 acc[4][2];
    #pragma unroll
    for (int i = 0; i < 4; i++)
        #pragma unroll
        for (int j = 0; j < 2; j++) acc[i][j] = (f32x4){0.f, 0.f, 0.f, 0.f};

    #define STAGE_O(buf, k0)                                        \
        do {                                                        \
            _Pragma("unroll")                                       \
            for (int is = 0; is < 4; is++)                          \
                gl16(aS[is] + (k0), &As[buf][is * 2048 + w * 512]); \
            _Pragma("unroll")                                       \
            for (int is = 0; is < 2; is++)                          \
                gl16(bS[is] + (k0), &Bs[buf][is * 2048 + w * 512]); \
        } while (0)

    STAGE_O(0, 0);
    for (int k = 0; k < 8; k++) {
        const int cur = k & 1;
        if (k < 7) {
            STAGE_O(cur ^ 1, (k + 1) * 64);
            asm volatile("s_waitcnt vmcnt(6)" ::: "memory");
        } else {
            asm volatile("s_waitcnt vmcnt(0)" ::: "memory");
        }
        asm volatile("s_barrier" ::: "memory");
        #pragma unroll
        for (int kc = 0; kc < 2; kc++) {
            const int ko = kc ? koff1 : koff0;
            bf16x8 a[4], bb[2];
            #pragma unroll
            for (int i = 0; i < 4; i++)
                a[i] = *(const bf16x8*)&As[cur][(wm + 16 * i + l15) * 64 + ko];
            #pragma unroll
            for (int j = 0; j < 2; j++)
                bb[j] = *(const bf16x8*)&Bs[cur][(wn + 16 * j + l15) * 64 + ko];
            #pragma unroll
            for (int i = 0; i < 4; i++)
                #pragma unroll
                for (int j = 0; j < 2; j++)
                    acc[i][j] = __builtin_amdgcn_mfma_f32_16x16x32_bf16(a[i], bb[j], acc[i][j], 0, 0, 0);
        }
        asm volatile("s_barrier" ::: "memory");
    }
    #undef STAGE_O

    #pragma unroll
    for (int j = 0; j < 2; j++) {
        int sg = n0 + wn + 16 * j + l15;
        #pragma unroll
        for (int i = 0; i < 4; i++) {
            int F = m0 + wm + 16 * i + quad * 4;
            float4 b4 = *(const float4*)&bo[F];
            float4 vv;
            vv.x = acc[i][j][0] + b4.x;
            vv.y = acc[i][j][1] + b4.y;
            vv.z = acc[i][j][2] + b4.z;
            vv.w = acc[i][j][3] + b4.w;
            *(float4*)&out[sg * 512 + F] = vv;
        }
    }
}

extern "C" void kernel_launch(void* const* d_in, const int* in_sizes, int n_in,
                              void* d_out, int out_size, void* d_ws, size_t ws_size,
                              hipStream_t stream)
{
    const float* query = (const float*)d_in[0];
    const float* value = (const float*)d_in[1];
    const int*   amask = (const int*)d_in[2];
    const float* Wq = (const float*)d_in[3];
    const float* bq = (const float*)d_in[4];
    const float* Wk = (const float*)d_in[5];
    const float* bk = (const float*)d_in[6];
    const float* Wv = (const float*)d_in[7];
    const float* bv = (const float*)d_in[8];
    const float* Wo = (const float*)d_in[9];
    const float* bo = (const float*)d_in[10];
    float* out = (float*)d_out;

    char* ws = (char*)d_ws;
    const size_t MB = 1 << 20;
    const size_t KB = 1 << 10;
    unsigned short* Xbq = (unsigned short*)(ws);                  // 8 MB bf16
    unsigned short* Xbv = (unsigned short*)(ws + 8 * MB);         // 8 MB
    unsigned short* Wtq = (unsigned short*)(ws + 16 * MB);        // 0.5 MB each
    unsigned short* Wtk = (unsigned short*)(ws + 16 * MB + MB / 2);
    unsigned short* Wtv = (unsigned short*)(ws + 17 * MB);
    unsigned short* Wto = (unsigned short*)(ws + 17 * MB + MB / 2);
    unsigned short* Qb  = (unsigned short*)(ws + 18 * MB);        // 8 MB (bh,s,d)
    unsigned short* Kb  = (unsigned short*)(ws + 26 * MB);        // 8 MB (bh,i,d) compacted
    unsigned short* VtG = (unsigned short*)(ws + 34 * MB);        // 8 MB (bh,d,i) compacted
    // aux region (42MB+): idx/masks — never aliased with anything.
    int*   idx1 = (int*)(ws + 42 * MB);                           // 32 KB
    float* Mf   = (float*)(ws + 42 * MB + 32 * KB);               // 32 KB
    float* Mc   = (float*)(ws + 42 * MB + 64 * KB);               // 32 KB
    int*   nv   = (int*)(ws + 42 * MB + 96 * KB);                 // 16 B
    // ctx reuses the Xbq region (dead after proj_qkv; flash writes it,
    // proj_out reads it — strictly stream-ordered).
    unsigned short* ctx = Xbq;                                    // 8 MB (b*s, h*d)

    pre_all<<<dim3(4353), 256, 0, stream>>>(query, value, amask,
                                            Wq, Wk, Wv, Wo,
                                            Xbq, Xbv, Wtq, Wtk, Wtv, Wto,
                                            idx1, nv, Mf, Mc);
    proj_qkv_mfma<<<dim3(128, 4, 3), 256, 0, stream>>>(Xbq, Xbv, Wtq, Wtk, Wtv,
                                                       bq, bk, bv, idx1, nv,
                                                       Qb, Kb, VtG);
    flash_mfma<<<dim3(1024), 256, 0, stream>>>(Qb, Kb, VtG, Mf, Mc, nv, ctx);
    proj_out_mfma<<<dim3(128, 4), 256, 0, stream>>>(ctx, Wto, bo, out);
}

// Round 8
// 186.755 us; speedup vs baseline: 1.1309x; 1.1309x over previous
//
#include <hip/hip_runtime.h>

#define B_ 4
#define S_ 2048
#define D_ 512
#define H_ 8

typedef __attribute__((ext_vector_type(8))) __bf16 bf16x8;
typedef __attribute__((ext_vector_type(4))) float f32x4;

#define NEGBIG  -1.442695040e9f          // -1e9 * log2(e): masks live in exp2 domain
#define QSCALE  0.18033688011112042f     // 0.125 * log2(e) folded into Q

// pack two floats -> two bf16 (RNE-ish, ties-up): 2 adds + 1 v_perm
__device__ __forceinline__ unsigned pack_rn(float a, float b) {
    union { float f; unsigned u; } ua, ub; ua.f = a; ub.f = b;
    return __builtin_amdgcn_perm(ub.u + 0x8000u, ua.u + 0x8000u, 0x07060302u);
}

// async global->LDS, 16B per lane. LDS dest = wave-uniform base + lane*16.
__device__ __forceinline__ void gl16(const void* g, void* l) {
    __builtin_amdgcn_global_load_lds(
        (const __attribute__((address_space(1))) unsigned int*)g,
        (__attribute__((address_space(3))) unsigned int*)l, 16, 0, 0);
}

// ---------------------------------------------------------------------------
// Fused preprocessing (one launch) — UNCHANGED from r5/r6.
// ---------------------------------------------------------------------------
__global__ __launch_bounds__(256) void pre_all(
    const float* __restrict__ q, const float* __restrict__ v,
    const int* __restrict__ am,
    const float* __restrict__ Wq, const float* __restrict__ Wk,
    const float* __restrict__ Wv, const float* __restrict__ Wo,
    unsigned short* __restrict__ xq, unsigned short* __restrict__ xv,
    unsigned short* __restrict__ Tq, unsigned short* __restrict__ Tk,
    unsigned short* __restrict__ Tv, unsigned short* __restrict__ To,
    int* __restrict__ idxc, int* __restrict__ nvout,
    float* __restrict__ Mf, float* __restrict__ Mc)
{
    const int bid = blockIdx.x;
    const int tid = threadIdx.x;

    if (bid < 4096) {                       // ---- cast_x ----
        const int z = bid >> 11, xb = bid & 2047;
        const float* src = z ? v : q;
        unsigned short* dst = z ? xv : xq;
        int i = (xb * 256 + tid) * 8;
        float4 f0 = *(const float4*)&src[i];
        float4 f1 = *(const float4*)&src[i + 4];
        uint4 o;
        o.x = pack_rn(f0.x, f0.y); o.y = pack_rn(f0.z, f0.w);
        o.z = pack_rn(f1.x, f1.y); o.w = pack_rn(f1.z, f1.w);
        *(uint4*)&dst[i] = o;
    } else if (bid < 4352) {                // ---- cast_wt ----
        int r = bid - 4096;
        int z = r >> 6, rem = r & 63;
        const float* W = (z == 0) ? Wq : (z == 1) ? Wk : (z == 2) ? Wv : Wo;
        unsigned short* T = (z == 0) ? Tq : (z == 1) ? Tk : (z == 2) ? Tv : To;
        int n0 = (rem & 7) * 64, k0 = (rem >> 3) * 64;

        __shared__ float Ts[64][69];
        #pragma unroll
        for (int it = 0; it < 4; it++) {
            int lin = tid + it * 256;
            int kr = lin >> 4, c4 = (lin & 15) * 4;
            float4 vv = *(const float4*)&W[(k0 + kr) * 512 + n0 + c4];
            Ts[kr][c4 + 0] = vv.x; Ts[kr][c4 + 1] = vv.y;
            Ts[kr][c4 + 2] = vv.z; Ts[kr][c4 + 3] = vv.w;
        }
        __syncthreads();
        int n = tid >> 2, kc = tid & 3;
        unsigned p[8];
        #pragma unroll
        for (int j = 0; j < 8; j++)
            p[j] = pack_rn(Ts[kc * 16 + 2 * j][n], Ts[kc * 16 + 2 * j + 1][n]);
        unsigned short* dst = &T[(n0 + n) * 512 + k0 + kc * 16];
        *(uint4*)dst       = *(uint4*)&p[0];
        *(uint4*)(dst + 8) = *(uint4*)&p[4];
    } else {                                // ---- compact + masks ----
        const int w = tid >> 6, lane = tid & 63;   // wave w = batch w
        const int* amb = am + w * 2048;
        int m[32];
        #pragma unroll
        for (int s = 0; s < 32; s++) m[s] = amb[s * 64 + lane];  // all issued up front

        int* ib = idxc + w * 2048;
        const unsigned long long lt = (1ULL << lane) - 1ULL;
        int base = 0;
        #pragma unroll
        for (int s = 0; s < 32; s++) {
            unsigned long long bal = __ballot(m[s] != 0);
            if (m[s]) ib[base + __popcll(bal & lt)] = s * 64 + lane;
            base += __popcll(bal);
        }
        const int nv = base;
        for (int i = nv + lane; i < 2048; i += 64) ib[i] = 0;   // pad -> row 0
        float* mfb = Mf + w * 2048;
        float* mcb = Mc + w * 2048;
        #pragma unroll
        for (int s = 0; s < 32; s++) {
            int i = s * 64 + lane;
            mfb[i] = m[s] ? 0.f : NEGBIG;
            mcb[i] = (i < nv) ? 0.f : NEGBIG;
        }
        if (lane == 0) nvout[w] = nv;
    }
}

// ---------------------------------------------------------------------------
// QKV projection GEMM — UNCHANGED from r6 (128x64 tiles, gl16 double-buffer
// with counted vmcnt, source-side XOR swizzle, fused gather, early-exit).
// ---------------------------------------------------------------------------
__global__ __launch_bounds__(256) void proj_qkv_mfma(
    const unsigned short* __restrict__ Xq, const unsigned short* __restrict__ Xv,
    const unsigned short* __restrict__ Wtq, const unsigned short* __restrict__ Wtk,
    const unsigned short* __restrict__ Wtv,
    const float* __restrict__ bq, const float* __restrict__ bk,
    const float* __restrict__ bv,
    const int* __restrict__ idxc, const int* __restrict__ nv1,
    unsigned short* __restrict__ Qb, unsigned short* __restrict__ Kb,
    unsigned short* __restrict__ VtG)
{
    const int z = blockIdx.z;
    const unsigned short* A  = (z == 0) ? Wtq : (z == 1) ? Wtk : Xv;
    const unsigned short* Bm = (z == 0) ? Xq  : (z == 1) ? Xv  : Wtv;
    const float* bias        = (z == 0) ? bq  : (z == 1) ? bk  : bv;
    const int lin0 = blockIdx.y * 128 + blockIdx.x;       // 0..511
    const int m0 = (z < 2) ? blockIdx.y * 128 : (lin0 >> 3) * 128;
    const int n0 = (z < 2) ? blockIdx.x * 64  : (lin0 & 7) * 64;

    // early-exit for blocks entirely in the dead compacted region
    if (z == 1) {
        int bb = n0 >> 11, cap = (nv1[bb] + 63) & ~63;
        if (cap < 64) cap = 64;
        if ((n0 & 2047) >= cap) return;
    }
    if (z == 2) {
        int bb = m0 >> 11, cap = (nv1[bb] + 63) & ~63;
        if (cap < 64) cap = 64;
        if ((m0 & 2047) >= cap) return;
    }

    const int tid = threadIdx.x;
    const int w = tid >> 6, lane = tid & 63;
    const int l15 = lane & 15, quad = lane >> 4;
    const int wm = (w >> 1) * 64, wn = (w & 1) * 32;

    __shared__ unsigned short As[2][128 * 64];
    __shared__ unsigned short Bs[2][64 * 64];

    // staging: srw = tid>>3 covers rows {is*32+srw}; source chunk pre-swizzled.
    const int srw  = tid >> 3;                       // 0..31
    const int csrc = (tid & 7) ^ (srw & 7);
    const unsigned short* aS[4];
    const unsigned short* bS[2];
    #pragma unroll
    for (int is = 0; is < 4; is++) {
        int ra = m0 + is * 32 + srw;
        long sa = ra;
        if (z == 2) { int bb = ra >> 11; sa = (long)bb * 2048 + idxc[bb * 2048 + (ra & 2047)]; }
        aS[is] = A + sa * 512 + csrc * 8;
    }
    #pragma unroll
    for (int is = 0; is < 2; is++) {
        int rb = n0 + is * 32 + srw;
        long sb = rb;
        if (z == 1) { int bb = rb >> 11; sb = (long)bb * 2048 + idxc[bb * 2048 + (rb & 2047)]; }
        bS[is] = Bm + sb * 512 + csrc * 8;
    }

    const int koff0 = ((quad    ) ^ (l15 & 7)) * 8;  // undo swizzle on read
    const int koff1 = ((quad + 4) ^ (l15 & 7)) * 8;

    f32x4 acc[4][2];
    #pragma unroll
    for (int i = 0; i < 4; i++)
        #pragma unroll
        for (int j = 0; j < 2; j++) acc[i][j] = (f32x4){0.f, 0.f, 0.f, 0.f};

    // ---- double-buffered K loop: 8 chunks of 64 ----
    #define STAGE_Q(buf, k0)                                        \
        do {                                                        \
            _Pragma("unroll")                                       \
            for (int is = 0; is < 4; is++)                          \
                gl16(aS[is] + (k0), &As[buf][is * 2048 + w * 512]); \
            _Pragma("unroll")                                       \
            for (int is = 0; is < 2; is++)                          \
                gl16(bS[is] + (k0), &Bs[buf][is * 2048 + w * 512]); \
        } while (0)

    STAGE_Q(0, 0);
    for (int k = 0; k < 8; k++) {
        const int cur = k & 1;
        if (k < 7) {
            STAGE_Q(cur ^ 1, (k + 1) * 64);
            asm volatile("s_waitcnt vmcnt(6)" ::: "memory");
        } else {
            asm volatile("s_waitcnt vmcnt(0)" ::: "memory");
        }
        asm volatile("s_barrier" ::: "memory");
        #pragma unroll
        for (int kc = 0; kc < 2; kc++) {
            const int ko = kc ? koff1 : koff0;
            bf16x8 a[4], bb[2];
            #pragma unroll
            for (int i = 0; i < 4; i++)
                a[i] = *(const bf16x8*)&As[cur][(wm + 16 * i + l15) * 64 + ko];
            #pragma unroll
            for (int j = 0; j < 2; j++)
                bb[j] = *(const bf16x8*)&Bs[cur][(wn + 16 * j + l15) * 64 + ko];
            #pragma unroll
            for (int i = 0; i < 4; i++)
                #pragma unroll
                for (int j = 0; j < 2; j++)
                    acc[i][j] = __builtin_amdgcn_mfma_f32_16x16x32_bf16(a[i], bb[j], acc[i][j], 0, 0, 0);
        }
        asm volatile("s_barrier" ::: "memory");
    }
    #undef STAGE_Q

    if (z == 2) {
        // V: cols = feature, rows = compacted s. ushort4 along s into (bh,d,i).
        #pragma unroll
        for (int j = 0; j < 2; j++) {
            int N = n0 + wn + 16 * j + l15;
            float bv_ = bias[N];
            int h = N >> 6, d = N & 63;
            #pragma unroll
            for (int i = 0; i < 4; i++) {
                int Mb = m0 + wm + 16 * i + quad * 4;
                int b = Mb >> 11, s = Mb & 2047;
                uint2 o;
                o.x = pack_rn(acc[i][j][0] + bv_, acc[i][j][1] + bv_);
                o.y = pack_rn(acc[i][j][2] + bv_, acc[i][j][3] + bv_);
                *(uint2*)&VtG[((b * H_ + h) * 64 + d) * 2048 + s] = o;
            }
        }
    } else {
        // Q/K: cols = s (K: compacted), rows = feature. ushort4 along d.
        unsigned short* dst = (z == 0) ? Qb : Kb;
        const float scale = (z == 0) ? QSCALE : 1.0f;
        #pragma unroll
        for (int j = 0; j < 2; j++) {
            int sg = n0 + wn + 16 * j + l15;
            int b = sg >> 11, s = sg & 2047;
            #pragma unroll
            for (int i = 0; i < 4; i++) {
                int F = m0 + wm + 16 * i + quad * 4;
                int h = F >> 6, d = F & 63;
                float4 b4 = *(const float4*)&bias[F];
                uint2 o;
                o.x = pack_rn((acc[i][j][0] + b4.x) * scale, (acc[i][j][1] + b4.y) * scale);
                o.y = pack_rn((acc[i][j][2] + b4.z) * scale, (acc[i][j][3] + b4.w) * scale);
                *(uint2*)&dst[((b * H_ + h) * 2048 + s) * 64 + d] = o;
            }
        }
    }
}

// ---------------------------------------------------------------------------
// MFMA flash attention over COMPACTED keys. r4's verified shape (block =
// (b,h, 128-q tile), 4 waves x 32q — r3/r7 proved this the right
// amortization point) but KVBLK=128: 128 keys per iteration (was 64).
// Iterations 16 -> 8: the fixed per-iteration serial chain (shfl reductions,
// rescale check, P LDS round-trip, staging commit, barrier skew) is paid
// half as often per key; per-key work is unchanged (no r7-style inflation).
// LDS 64 KB (still 2 blocks/CU, grid-capped). V loads split into two issue
// halves to cap the VGPR live-range. Same XOR swizzles, mask-as-C-init,
// defer-max, setprio.
// ---------------------------------------------------------------------------
__global__ __launch_bounds__(256, 2) void flash_mfma(
    const unsigned short* __restrict__ Qg, const unsigned short* __restrict__ Kg,
    const unsigned short* __restrict__ VtG, const float* __restrict__ Mf,
    const float* __restrict__ Mc, const int* __restrict__ nvalid,
    unsigned short* __restrict__ ctxB)
{
    const int bid = blockIdx.x;                  // 0..511
    const int xcd = bid & 7, idx = bid >> 3;     // XCD x owns bh 4x..4x+3
    const int bh = xcd * 4 + (idx & 3);
    const int q0 = (idx >> 2) * 128;
    const int b = bh >> 3, h = bh & 7;

    const int tid = threadIdx.x;
    const int w = tid >> 6, lane = tid & 63;
    const int l15 = lane & 15, quad = lane >> 4;
    const int swz = l15 & 7;

    __shared__ unsigned short Ks[2][128 * 64];   // 128-key tile, XOR-swizzled
    __shared__ unsigned short Ps[4][32 * 128];   // per-wave P [q][128 keys]
    unsigned short* pw = &Ps[w][0];

    const int nv = nvalid[b];
    int ntiles = (nv + 127) >> 7;
    if (ntiles < 1) ntiles = 1;

    const float* mfb = Mf + b * 2048;
    const float* mcp = Mc + b * 2048 + quad * 4;

    // Q fragments (B-operand) + query mask, resident
    bf16x8 qf[2][2];
    float mq[2];
    #pragma unroll
    for (int qb = 0; qb < 2; qb++) {
        int qrow = q0 + w * 32 + qb * 16 + l15;
        const unsigned short* p = &Qg[((long)bh * 2048 + qrow) * 64 + quad * 8];
        qf[qb][0] = *(const bf16x8*)p;
        qf[qb][1] = *(const bf16x8*)(p + 32);
        mq[qb] = mfb[qrow];
    }

    // V row pointers (bh,d,i layout)
    const unsigned short* vp[4];
    #pragma unroll
    for (int i = 0; i < 4; i++)
        vp[i] = VtG + ((long)bh * 64 + i * 16 + l15) * 2048 + quad * 8;

    // K staging: thread -> row = tid>>1 (0..127), 4 chunks from sch=(tid&1)*4
    const int srow = tid >> 1;
    const int sch  = (tid & 1) * 4;
    const unsigned short* kgb = Kg + (long)bh * 2048 * 64;
    int swk[4];
    #pragma unroll
    for (int j = 0; j < 4; j++)
        swk[j] = srow * 64 + ((sch + j) ^ (srow & 7)) * 8;

    // preamble: stage tile 0 into Ks[0]
    #pragma unroll
    for (int j = 0; j < 4; j++)
        *(uint4*)&Ks[0][swk[j]] = *(const uint4*)&kgb[srow * 64 + (sch + j) * 8];

    // swizzled K-fragment chunk offsets (d-chunks 0..7)
    const int koff0 = ((quad    ) ^ swz) * 8;
    const int koff1 = ((quad + 4) ^ swz) * 8;

    f32x4 accO[2][4];
    #pragma unroll
    for (int qb = 0; qb < 2; qb++)
        #pragma unroll
        for (int dt = 0; dt < 4; dt++) accO[qb][dt] = (f32x4){0.f, 0.f, 0.f, 0.f};
    float mi[2] = {-3.0e38f, -3.0e38f};
    float li[2] = {0.f, 0.f};

    __syncthreads();

    for (int t = 0; t < ntiles; t++) {
        const int kt = t * 128;
        const int ktn = (t + 1 < ntiles) ? kt + 128 : kt;
        const int cur = t & 1, nxt = cur ^ 1;

        // [A] issue global loads: V first half + K staging for NEXT + masks
        bf16x8 vfA[4][2], vfB[4][2];
        #pragma unroll
        for (int dt = 0; dt < 4; dt++) {
            vfA[dt][0] = *(const bf16x8*)(vp[dt] + kt);
            vfA[dt][1] = *(const bf16x8*)(vp[dt] + kt + 32);
        }
        uint4 kst[4];
        #pragma unroll
        for (int j = 0; j < 4; j++)
            kst[j] = *(const uint4*)&kgb[(ktn + srow) * 64 + (sch + j) * 8];
        f32x4 kmf[8];
        #pragma unroll
        for (int nt = 0; nt < 8; nt++)
            kmf[nt] = *(const f32x4*)(mcp + kt + nt * 16);

        // [C] QK over 128 keys: S^T (rows=key, cols=q), masks as C-init
        f32x4 sc[2][8];
        #pragma unroll
        for (int qb = 0; qb < 2; qb++)
            #pragma unroll
            for (int nt = 0; nt < 8; nt++) {
                f32x4 c = kmf[nt];
                c[0] += mq[qb]; c[1] += mq[qb]; c[2] += mq[qb]; c[3] += mq[qb];
                sc[qb][nt] = c;
            }
        __builtin_amdgcn_s_setprio(1);
        #pragma unroll
        for (int nt = 0; nt < 8; nt++) {
            bf16x8 kf0 = *(const bf16x8*)&Ks[cur][(nt * 16 + l15) * 64 + koff0];
            bf16x8 kf1 = *(const bf16x8*)&Ks[cur][(nt * 16 + l15) * 64 + koff1];
            #pragma unroll
            for (int qb = 0; qb < 2; qb++) {
                sc[qb][nt] = __builtin_amdgcn_mfma_f32_16x16x32_bf16(
                    kf0, qf[qb][0], sc[qb][nt], 0, 0, 0);
                sc[qb][nt] = __builtin_amdgcn_mfma_f32_16x16x32_bf16(
                    kf1, qf[qb][1], sc[qb][nt], 0, 0, 0);
            }
        }
        __builtin_amdgcn_s_setprio(0);

        // issue V second half now — hides under softmax
        #pragma unroll
        for (int dt = 0; dt < 4; dt++) {
            vfB[dt][0] = *(const bf16x8*)(vp[dt] + kt + 64);
            vfB[dt][1] = *(const bf16x8*)(vp[dt] + kt + 96);
        }

        // [D] online softmax over 128 keys (one reduce pass, one rescale check)
        #pragma unroll
        for (int qb = 0; qb < 2; qb++) {
            float mloc = fmaxf(fmaxf(sc[qb][0][0], sc[qb][0][1]),
                               fmaxf(sc[qb][0][2], sc[qb][0][3]));
            #pragma unroll
            for (int nt = 1; nt < 8; nt++)
                mloc = fmaxf(mloc, fmaxf(fmaxf(sc[qb][nt][0], sc[qb][nt][1]),
                                         fmaxf(sc[qb][nt][2], sc[qb][nt][3])));
            mloc = fmaxf(mloc, __shfl_xor(mloc, 16));
            mloc = fmaxf(mloc, __shfl_xor(mloc, 32));

            float mn = mi[qb];
            if (!__all(mloc <= mn + 4.f)) {      // defer-max: P bounded by 2^4
                float mo = mn;
                mn = fmaxf(mo, mloc);
                float alpha = __builtin_amdgcn_exp2f(mo - mn);
                li[qb] *= alpha;
                #pragma unroll
                for (int dt = 0; dt < 4; dt++) {
                    accO[qb][dt][0] *= alpha; accO[qb][dt][1] *= alpha;
                    accO[qb][dt][2] *= alpha; accO[qb][dt][3] *= alpha;
                }
                mi[qb] = mn;
            }

            float ps = 0.f;
            const int prbase = (qb * 16 + l15) * 128;
            #pragma unroll
            for (int nt = 0; nt < 8; nt++) {
                float p0 = __builtin_amdgcn_exp2f(sc[qb][nt][0] - mn);
                float p1 = __builtin_amdgcn_exp2f(sc[qb][nt][1] - mn);
                float p2 = __builtin_amdgcn_exp2f(sc[qb][nt][2] - mn);
                float p3 = __builtin_amdgcn_exp2f(sc[qb][nt][3] - mn);
                ps += (p0 + p1) + (p2 + p3);
                // keys nt*16+quad*4..+3 -> chunk 2nt+(quad>>1) of 16, sub (quad&1)*4
                uint2 pp;
                pp.x = pack_rn(p0, p1);
                pp.y = pack_rn(p2, p3);
                *(uint2*)&pw[prbase + ((2 * nt + (quad >> 1)) ^ swz) * 8 + (quad & 1) * 4] = pp;
            }
            ps += __shfl_xor(ps, 16);
            ps += __shfl_xor(ps, 32);
            li[qb] += ps;
        }

        // [E] PV: O^T += Vt (A) x P^T (B), 4 k-slices of 32 keys
        #pragma unroll
        for (int qb = 0; qb < 2; qb++) {
            bf16x8 pf[4];
            #pragma unroll
            for (int kc = 0; kc < 4; kc++)
                pf[kc] = *(const bf16x8*)&pw[(qb * 16 + l15) * 128 + ((quad + 4 * kc) ^ swz) * 8];
            __builtin_amdgcn_s_setprio(1);
            #pragma unroll
            for (int dt = 0; dt < 4; dt++) {
                accO[qb][dt] = __builtin_amdgcn_mfma_f32_16x16x32_bf16(
                    vfA[dt][0], pf[0], accO[qb][dt], 0, 0, 0);
                accO[qb][dt] = __builtin_amdgcn_mfma_f32_16x16x32_bf16(
                    vfA[dt][1], pf[1], accO[qb][dt], 0, 0, 0);
                accO[qb][dt] = __builtin_amdgcn_mfma_f32_16x16x32_bf16(
                    vfB[dt][0], pf[2], accO[qb][dt], 0, 0, 0);
                accO[qb][dt] = __builtin_amdgcn_mfma_f32_16x16x32_bf16(
                    vfB[dt][1], pf[3], accO[qb][dt], 0, 0, 0);
            }
            __builtin_amdgcn_s_setprio(0);
        }

        // [F] commit next K tile to LDS (waits the [A] loads), [G] barrier
        #pragma unroll
        for (int j = 0; j < 4; j++)
            *(uint4*)&Ks[nxt][swk[j]] = kst[j];
        __syncthreads();
    }

    #pragma unroll
    for (int qb = 0; qb < 2; qb++) {
        float inv = 1.f / li[qb];
        int q = q0 + w * 32 + qb * 16 + l15;
        int obase = (b * 2048 + q) * 512 + h * 64 + quad * 4;
        #pragma unroll
        for (int dt = 0; dt < 4; dt++) {
            uint2 o;
            o.x = pack_rn(accO[qb][dt][0] * inv, accO[qb][dt][1] * inv);
            o.y = pack_rn(accO[qb][dt][2] * inv, accO[qb][dt][3] * inv);
            *(uint2*)&ctxB[obase + dt * 16] = o;
        }
    }
}

// ---------------------------------------------------------------------------
// Output projection — UNCHANGED from r6 (128x64 tiles, gl16 DB, counted vmcnt).
// ---------------------------------------------------------------------------
__global__ __launch_bounds__(256) void proj_out_mfma(
    const unsigned short* __restrict__ ctxB, const unsigned short* __restrict__ Wto,
    const float* __restrict__ bo, float* __restrict__ out)
{
    const int m0 = blockIdx.y * 128, n0 = blockIdx.x * 64;
    const int tid = threadIdx.x;
    const int w = tid >> 6, lane = tid & 63;
    const int l15 = lane & 15, quad = lane >> 4;
    const int wm = (w >> 1) * 64, wn = (w & 1) * 32;

    __shared__ unsigned short As[2][128 * 64];
    __shared__ unsigned short Bs[2][64 * 64];

    const int srw  = tid >> 3;
    const int csrc = (tid & 7) ^ (srw & 7);
    const unsigned short* aS[4];
    const unsigned short* bS[2];
    #pragma unroll
    for (int is = 0; is < 4; is++)
        aS[is] = Wto  + (long)(m0 + is * 32 + srw) * 512 + csrc * 8;
    #pragma unroll
    for (int is = 0; is < 2; is++)
        bS[is] = ctxB + (long)(n0 + is * 32 + srw) * 512 + csrc * 8;

    const int koff0 = ((quad    ) ^ (l15 & 7)) * 8;
    const int koff1 = ((quad + 4) ^ (l15 & 7)) * 8;

    f32x4 acc[4][2];
    #pragma unroll
    for (int i = 0; i < 4; i++)
        #pragma unroll
        for (int j = 0; j < 2; j++) acc[i][j] = (f32x4){0.f, 0.f, 0.f, 0.f};

    #define STAGE_O(buf, k0)                                        \
        do {                                                        \
            _Pragma("unroll")                                       \
            for (int is = 0; is < 4; is++)                          \
                gl16(aS[is] + (k0), &As[buf][is * 2048 + w * 512]); \
            _Pragma("unroll")                                       \
            for (int is = 0; is < 2; is++)                          \
                gl16(bS[is] + (k0), &Bs[buf][is * 2048 + w * 512]); \
        } while (0)

    STAGE_O(0, 0);
    for (int k = 0; k < 8; k++) {
        const int cur = k & 1;
        if (k < 7) {
            STAGE_O(cur ^ 1, (k + 1) * 64);
            asm volatile("s_waitcnt vmcnt(6)" ::: "memory");
        } else {
            asm volatile("s_waitcnt vmcnt(0)" ::: "memory");
        }
        asm volatile("s_barrier" ::: "memory");
        #pragma unroll
        for (int kc = 0; kc < 2; kc++) {
            const int ko = kc ? koff1 : koff0;
            bf16x8 a[4], bb[2];
            #pragma unroll
            for (int i = 0; i < 4; i++)
                a[i] = *(const bf16x8*)&As[cur][(wm + 16 * i + l15) * 64 + ko];
            #pragma unroll
            for (int j = 0; j < 2; j++)
                bb[j] = *(const bf16x8*)&Bs[cur][(wn + 16 * j + l15) * 64 + ko];
            #pragma unroll
            for (int i = 0; i < 4; i++)
                #pragma unroll
                for (int j = 0; j < 2; j++)
                    acc[i][j] = __builtin_amdgcn_mfma_f32_16x16x32_bf16(a[i], bb[j], acc[i][j], 0, 0, 0);
        }
        asm volatile("s_barrier" ::: "memory");
    }
    #undef STAGE_O

    #pragma unroll
    for (int j = 0; j < 2; j++) {
        int sg = n0 + wn + 16 * j + l15;
        #pragma unroll
        for (int i = 0; i < 4; i++) {
            int F = m0 + wm + 16 * i + quad * 4;
            float4 b4 = *(const float4*)&bo[F];
            float4 vv;
            vv.x = acc[i][j][0] + b4.x;
            vv.y = acc[i][j][1] + b4.y;
            vv.z = acc[i][j][2] + b4.z;
            vv.w = acc[i][j][3] + b4.w;
            *(float4*)&out[sg * 512 + F] = vv;
        }
    }
}

extern "C" void kernel_launch(void* const* d_in, const int* in_sizes, int n_in,
                              void* d_out, int out_size, void* d_ws, size_t ws_size,
                              hipStream_t stream)
{
    const float* query = (const float*)d_in[0];
    const float* value = (const float*)d_in[1];
    const int*   amask = (const int*)d_in[2];
    const float* Wq = (const float*)d_in[3];
    const float* bq = (const float*)d_in[4];
    const float* Wk = (const float*)d_in[5];
    const float* bk = (const float*)d_in[6];
    const float* Wv = (const float*)d_in[7];
    const float* bv = (const float*)d_in[8];
    const float* Wo = (const float*)d_in[9];
    const float* bo = (const float*)d_in[10];
    float* out = (float*)d_out;

    char* ws = (char*)d_ws;
    const size_t MB = 1 << 20;
    const size_t KB = 1 << 10;
    unsigned short* Xbq = (unsigned short*)(ws);                  // 8 MB bf16
    unsigned short* Xbv = (unsigned short*)(ws + 8 * MB);         // 8 MB
    unsigned short* Wtq = (unsigned short*)(ws + 16 * MB);        // 0.5 MB each
    unsigned short* Wtk = (unsigned short*)(ws + 16 * MB + MB / 2);
    unsigned short* Wtv = (unsigned short*)(ws + 17 * MB);
    unsigned short* Wto = (unsigned short*)(ws + 17 * MB + MB / 2);
    unsigned short* Qb  = (unsigned short*)(ws + 18 * MB);        // 8 MB (bh,s,d)
    unsigned short* Kb  = (unsigned short*)(ws + 26 * MB);        // 8 MB (bh,i,d) compacted
    unsigned short* VtG = (unsigned short*)(ws + 34 * MB);        // 8 MB (bh,d,i) compacted
    // aux region (42MB+): idx/masks — never aliased with anything.
    int*   idx1 = (int*)(ws + 42 * MB);                           // 32 KB
    float* Mf   = (float*)(ws + 42 * MB + 32 * KB);               // 32 KB
    float* Mc   = (float*)(ws + 42 * MB + 64 * KB);               // 32 KB
    int*   nv   = (int*)(ws + 42 * MB + 96 * KB);                 // 16 B
    // ctx reuses the Xbq region (dead after proj_qkv; flash writes it,
    // proj_out reads it — strictly stream-ordered).
    unsigned short* ctx = Xbq;                                    // 8 MB (b*s, h*d)

    pre_all<<<dim3(4353), 256, 0, stream>>>(query, value, amask,
                                            Wq, Wk, Wv, Wo,
                                            Xbq, Xbv, Wtq, Wtk, Wtv, Wto,
                                            idx1, nv, Mf, Mc);
    proj_qkv_mfma<<<dim3(128, 4, 3), 256, 0, stream>>>(Xbq, Xbv, Wtq, Wtk, Wtv,
                                                       bq, bk, bv, idx1, nv,
                                                       Qb, Kb, VtG);
    flash_mfma<<<dim3(512), 256, 0, stream>>>(Qb, Kb, VtG, Mf, Mc, nv, ctx);
    proj_out_mfma<<<dim3(128, 4), 256, 0, stream>>>(ctx, Wto, bo, out);
}

// Round 9
// 180.306 us; speedup vs baseline: 1.1714x; 1.0358x over previous
//
#include <hip/hip_runtime.h>

#define B_ 4
#define S_ 2048
#define D_ 512
#define H_ 8

typedef __attribute__((ext_vector_type(8))) __bf16 bf16x8;
typedef __attribute__((ext_vector_type(4))) float f32x4;

#define NEGBIG  -1.442695040e9f          // -1e9 * log2(e): masks live in exp2 domain
#define QSCALE  0.18033688011112042f     // 0.125 * log2(e) folded into Q

// pack two floats -> two bf16 (RNE-ish, ties-up): 2 adds + 1 v_perm
__device__ __forceinline__ unsigned pack_rn(float a, float b) {
    union { float f; unsigned u; } ua, ub; ua.f = a; ub.f = b;
    return __builtin_amdgcn_perm(ub.u + 0x8000u, ua.u + 0x8000u, 0x07060302u);
}

// async global->LDS, 16B per lane. LDS dest = wave-uniform base + lane*16.
__device__ __forceinline__ void gl16(const void* g, void* l) {
    __builtin_amdgcn_global_load_lds(
        (const __attribute__((address_space(1))) unsigned int*)g,
        (__attribute__((address_space(3))) unsigned int*)l, 16, 0, 0);
}

// ---------------------------------------------------------------------------
// Fused preprocessing (one launch) — UNCHANGED from r5/r6.
// ---------------------------------------------------------------------------
__global__ __launch_bounds__(256) void pre_all(
    const float* __restrict__ q, const float* __restrict__ v,
    const int* __restrict__ am,
    const float* __restrict__ Wq, const float* __restrict__ Wk,
    const float* __restrict__ Wv, const float* __restrict__ Wo,
    unsigned short* __restrict__ xq, unsigned short* __restrict__ xv,
    unsigned short* __restrict__ Tq, unsigned short* __restrict__ Tk,
    unsigned short* __restrict__ Tv, unsigned short* __restrict__ To,
    int* __restrict__ idxc, int* __restrict__ nvout,
    float* __restrict__ Mf, float* __restrict__ Mc)
{
    const int bid = blockIdx.x;
    const int tid = threadIdx.x;

    if (bid < 4096) {                       // ---- cast_x ----
        const int z = bid >> 11, xb = bid & 2047;
        const float* src = z ? v : q;
        unsigned short* dst = z ? xv : xq;
        int i = (xb * 256 + tid) * 8;
        float4 f0 = *(const float4*)&src[i];
        float4 f1 = *(const float4*)&src[i + 4];
        uint4 o;
        o.x = pack_rn(f0.x, f0.y); o.y = pack_rn(f0.z, f0.w);
        o.z = pack_rn(f1.x, f1.y); o.w = pack_rn(f1.z, f1.w);
        *(uint4*)&dst[i] = o;
    } else if (bid < 4352) {                // ---- cast_wt ----
        int r = bid - 4096;
        int z = r >> 6, rem = r & 63;
        const float* W = (z == 0) ? Wq : (z == 1) ? Wk : (z == 2) ? Wv : Wo;
        unsigned short* T = (z == 0) ? Tq : (z == 1) ? Tk : (z == 2) ? Tv : To;
        int n0 = (rem & 7) * 64, k0 = (rem >> 3) * 64;

        __shared__ float Ts[64][69];
        #pragma unroll
        for (int it = 0; it < 4; it++) {
            int lin = tid + it * 256;
            int kr = lin >> 4, c4 = (lin & 15) * 4;
            float4 vv = *(const float4*)&W[(k0 + kr) * 512 + n0 + c4];
            Ts[kr][c4 + 0] = vv.x; Ts[kr][c4 + 1] = vv.y;
            Ts[kr][c4 + 2] = vv.z; Ts[kr][c4 + 3] = vv.w;
        }
        __syncthreads();
        int n = tid >> 2, kc = tid & 3;
        unsigned p[8];
        #pragma unroll
        for (int j = 0; j < 8; j++)
            p[j] = pack_rn(Ts[kc * 16 + 2 * j][n], Ts[kc * 16 + 2 * j + 1][n]);
        unsigned short* dst = &T[(n0 + n) * 512 + k0 + kc * 16];
        *(uint4*)dst       = *(uint4*)&p[0];
        *(uint4*)(dst + 8) = *(uint4*)&p[4];
    } else {                                // ---- compact + masks ----
        const int w = tid >> 6, lane = tid & 63;   // wave w = batch w
        const int* amb = am + w * 2048;
        int m[32];
        #pragma unroll
        for (int s = 0; s < 32; s++) m[s] = amb[s * 64 + lane];  // all issued up front

        int* ib = idxc + w * 2048;
        const unsigned long long lt = (1ULL << lane) - 1ULL;
        int base = 0;
        #pragma unroll
        for (int s = 0; s < 32; s++) {
            unsigned long long bal = __ballot(m[s] != 0);
            if (m[s]) ib[base + __popcll(bal & lt)] = s * 64 + lane;
            base += __popcll(bal);
        }
        const int nv = base;
        for (int i = nv + lane; i < 2048; i += 64) ib[i] = 0;   // pad -> row 0
        float* mfb = Mf + w * 2048;
        float* mcb = Mc + w * 2048;
        #pragma unroll
        for (int s = 0; s < 32; s++) {
            int i = s * 64 + lane;
            mfb[i] = m[s] ? 0.f : NEGBIG;
            mcb[i] = (i < nv) ? 0.f : NEGBIG;
        }
        if (lane == 0) nvout[w] = nv;
    }
}

// ---------------------------------------------------------------------------
// QKV projection GEMM — UNCHANGED from r6 (128x64 tiles, gl16 double-buffer
// with counted vmcnt, source-side XOR swizzle, fused gather, early-exit).
// ---------------------------------------------------------------------------
__global__ __launch_bounds__(256) void proj_qkv_mfma(
    const unsigned short* __restrict__ Xq, const unsigned short* __restrict__ Xv,
    const unsigned short* __restrict__ Wtq, const unsigned short* __restrict__ Wtk,
    const unsigned short* __restrict__ Wtv,
    const float* __restrict__ bq, const float* __restrict__ bk,
    const float* __restrict__ bv,
    const int* __restrict__ idxc, const int* __restrict__ nv1,
    unsigned short* __restrict__ Qb, unsigned short* __restrict__ Kb,
    unsigned short* __restrict__ VtG)
{
    const int z = blockIdx.z;
    const unsigned short* A  = (z == 0) ? Wtq : (z == 1) ? Wtk : Xv;
    const unsigned short* Bm = (z == 0) ? Xq  : (z == 1) ? Xv  : Wtv;
    const float* bias        = (z == 0) ? bq  : (z == 1) ? bk  : bv;
    const int lin0 = blockIdx.y * 128 + blockIdx.x;       // 0..511
    const int m0 = (z < 2) ? blockIdx.y * 128 : (lin0 >> 3) * 128;
    const int n0 = (z < 2) ? blockIdx.x * 64  : (lin0 & 7) * 64;

    // early-exit for blocks entirely in the dead compacted region
    if (z == 1) {
        int bb = n0 >> 11, cap = (nv1[bb] + 63) & ~63;
        if (cap < 64) cap = 64;
        if ((n0 & 2047) >= cap) return;
    }
    if (z == 2) {
        int bb = m0 >> 11, cap = (nv1[bb] + 63) & ~63;
        if (cap < 64) cap = 64;
        if ((m0 & 2047) >= cap) return;
    }

    const int tid = threadIdx.x;
    const int w = tid >> 6, lane = tid & 63;
    const int l15 = lane & 15, quad = lane >> 4;
    const int wm = (w >> 1) * 64, wn = (w & 1) * 32;

    __shared__ unsigned short As[2][128 * 64];
    __shared__ unsigned short Bs[2][64 * 64];

    // staging: srw = tid>>3 covers rows {is*32+srw}; source chunk pre-swizzled.
    const int srw  = tid >> 3;                       // 0..31
    const int csrc = (tid & 7) ^ (srw & 7);
    const unsigned short* aS[4];
    const unsigned short* bS[2];
    #pragma unroll
    for (int is = 0; is < 4; is++) {
        int ra = m0 + is * 32 + srw;
        long sa = ra;
        if (z == 2) { int bb = ra >> 11; sa = (long)bb * 2048 + idxc[bb * 2048 + (ra & 2047)]; }
        aS[is] = A + sa * 512 + csrc * 8;
    }
    #pragma unroll
    for (int is = 0; is < 2; is++) {
        int rb = n0 + is * 32 + srw;
        long sb = rb;
        if (z == 1) { int bb = rb >> 11; sb = (long)bb * 2048 + idxc[bb * 2048 + (rb & 2047)]; }
        bS[is] = Bm + sb * 512 + csrc * 8;
    }

    const int koff0 = ((quad    ) ^ (l15 & 7)) * 8;  // undo swizzle on read
    const int koff1 = ((quad + 4) ^ (l15 & 7)) * 8;

    f32x4 acc[4][2];
    #pragma unroll
    for (int i = 0; i < 4; i++)
        #pragma unroll
        for (int j = 0; j < 2; j++) acc[i][j] = (f32x4){0.f, 0.f, 0.f, 0.f};

    // ---- double-buffered K loop: 8 chunks of 64 ----
    #define STAGE_Q(buf, k0)                                        \
        do {                                                        \
            _Pragma("unroll")                                       \
            for (int is = 0; is < 4; is++)                          \
                gl16(aS[is] + (k0), &As[buf][is * 2048 + w * 512]); \
            _Pragma("unroll")                                       \
            for (int is = 0; is < 2; is++)                          \
                gl16(bS[is] + (k0), &Bs[buf][is * 2048 + w * 512]); \
        } while (0)

    STAGE_Q(0, 0);
    for (int k = 0; k < 8; k++) {
        const int cur = k & 1;
        if (k < 7) {
            STAGE_Q(cur ^ 1, (k + 1) * 64);
            asm volatile("s_waitcnt vmcnt(6)" ::: "memory");
        } else {
            asm volatile("s_waitcnt vmcnt(0)" ::: "memory");
        }
        asm volatile("s_barrier" ::: "memory");
        #pragma unroll
        for (int kc = 0; kc < 2; kc++) {
            const int ko = kc ? koff1 : koff0;
            bf16x8 a[4], bb[2];
            #pragma unroll
            for (int i = 0; i < 4; i++)
                a[i] = *(const bf16x8*)&As[cur][(wm + 16 * i + l15) * 64 + ko];
            #pragma unroll
            for (int j = 0; j < 2; j++)
                bb[j] = *(const bf16x8*)&Bs[cur][(wn + 16 * j + l15) * 64 + ko];
            #pragma unroll
            for (int i = 0; i < 4; i++)
                #pragma unroll
                for (int j = 0; j < 2; j++)
                    acc[i][j] = __builtin_amdgcn_mfma_f32_16x16x32_bf16(a[i], bb[j], acc[i][j], 0, 0, 0);
        }
        asm volatile("s_barrier" ::: "memory");
    }
    #undef STAGE_Q

    if (z == 2) {
        // V: cols = feature, rows = compacted s. ushort4 along s into (bh,d,i).
        #pragma unroll
        for (int j = 0; j < 2; j++) {
            int N = n0 + wn + 16 * j + l15;
            float bv_ = bias[N];
            int h = N >> 6, d = N & 63;
            #pragma unroll
            for (int i = 0; i < 4; i++) {
                int Mb = m0 + wm + 16 * i + quad * 4;
                int b = Mb >> 11, s = Mb & 2047;
                uint2 o;
                o.x = pack_rn(acc[i][j][0] + bv_, acc[i][j][1] + bv_);
                o.y = pack_rn(acc[i][j][2] + bv_, acc[i][j][3] + bv_);
                *(uint2*)&VtG[((b * H_ + h) * 64 + d) * 2048 + s] = o;
            }
        }
    } else {
        // Q/K: cols = s (K: compacted), rows = feature. ushort4 along d.
        unsigned short* dst = (z == 0) ? Qb : Kb;
        const float scale = (z == 0) ? QSCALE : 1.0f;
        #pragma unroll
        for (int j = 0; j < 2; j++) {
            int sg = n0 + wn + 16 * j + l15;
            int b = sg >> 11, s = sg & 2047;
            #pragma unroll
            for (int i = 0; i < 4; i++) {
                int F = m0 + wm + 16 * i + quad * 4;
                int h = F >> 6, d = F & 63;
                float4 b4 = *(const float4*)&bias[F];
                uint2 o;
                o.x = pack_rn((acc[i][j][0] + b4.x) * scale, (acc[i][j][1] + b4.y) * scale);
                o.y = pack_rn((acc[i][j][2] + b4.z) * scale, (acc[i][j][3] + b4.w) * scale);
                *(uint2*)&dst[((b * H_ + h) * 2048 + s) * 64 + d] = o;
            }
        }
    }
}

// ---------------------------------------------------------------------------
// MFMA flash attention over COMPACTED keys — r6's verified KVBLK=64 shape
// (block = (b,h, 128-q tile), 4 waves x 32q), now SOFTWARE-PIPELINED (T15):
// each iteration runs QK(t+1) MFMAs right after the barrier, THEN softmax(t)
// on the previous tile's scores (register-only VALU, independent of the
// in-flight QK MFMAs -> the two pipes overlap within the wave), then PV(t).
// QK(t+1) results are consumed one iteration later, after commit+barrier
// have drained the MFMA pipe. Two sc buffers with STATIC names (scA/scB,
// unroll-by-2). K register-preload is one tile deeper (K(t+2) issued in
// iter t). One barrier/iter; Ks write-after-read separated by the previous
// iteration's barrier. Per-tile math, mask C-init, key order, rescale
// sequence bit-identical to r6 -> same absmax expected.
// ---------------------------------------------------------------------------
__global__ __launch_bounds__(256, 2) void flash_mfma(
    const unsigned short* __restrict__ Qg, const unsigned short* __restrict__ Kg,
    const unsigned short* __restrict__ VtG, const float* __restrict__ Mf,
    const float* __restrict__ Mc, const int* __restrict__ nvalid,
    unsigned short* __restrict__ ctxB)
{
    const int bid = blockIdx.x;                  // 0..511
    const int xcd = bid & 7, idx = bid >> 3;     // XCD x owns bh 4x..4x+3
    const int bh = xcd * 4 + (idx & 3);
    const int q0 = (idx >> 2) * 128;
    const int b = bh >> 3, h = bh & 7;

    const int tid = threadIdx.x;
    const int w = tid >> 6, lane = tid & 63;
    const int l15 = lane & 15, quad = lane >> 4;
    const int swz = l15 & 7;

    __shared__ unsigned short Ks[2][64 * 64];    // pad-free, XOR-chunk-swizzled
    __shared__ unsigned short Ps[4][32 * 64];    // per-wave P, same swizzle
    unsigned short* pw = &Ps[w][0];

    const int nv = nvalid[b];
    int ntiles = (nv + 63) >> 6;
    if (ntiles < 1) ntiles = 1;

    const float* mfb = Mf + b * 2048;
    const float* mcp = Mc + b * 2048 + quad * 4;

    // Q fragments (B-operand) + query mask, resident
    bf16x8 qf[2][2];
    float mq[2];
    #pragma unroll
    for (int qb = 0; qb < 2; qb++) {
        int qrow = q0 + w * 32 + qb * 16 + l15;
        const unsigned short* p = &Qg[((long)bh * 2048 + qrow) * 64 + quad * 8];
        qf[qb][0] = *(const bf16x8*)p;
        qf[qb][1] = *(const bf16x8*)(p + 32);
        mq[qb] = mfb[qrow];
    }

    // V row pointers (bh,d,i layout)
    const unsigned short* vp[4];
    #pragma unroll
    for (int i = 0; i < 4; i++)
        vp[i] = VtG + ((long)bh * 64 + i * 16 + l15) * 2048 + quad * 8;

    // K staging: thread -> (row = tid>>2, chunks (tid&3)*2, +1) of 64x64 tile
    const int srow = tid >> 2;
    const int sch  = (tid & 3) * 2;
    const unsigned short* kgb = Kg + (long)bh * 2048 * 64;
    const int sw0 = srow * 64 + ((sch    ) ^ (srow & 7)) * 8;
    const int sw1 = srow * 64 + ((sch + 1) ^ (srow & 7)) * 8;

    // stage K(0) into Ks[0]; preload K(1) into registers
    {
        uint4 a = *(const uint4*)&kgb[srow * 64 + sch * 8];
        uint4 c = *(const uint4*)&kgb[srow * 64 + sch * 8 + 8];
        *(uint4*)&Ks[0][sw0] = a;
        *(uint4*)&Ks[0][sw1] = c;
    }
    const int kt1 = (ntiles > 1) ? 64 : 0;
    uint4 kstA = *(const uint4*)&kgb[(kt1 + srow) * 64 + sch * 8];
    uint4 kstB = *(const uint4*)&kgb[(kt1 + srow) * 64 + sch * 8 + 8];

    // swizzled fragment-read chunk offsets (kc=0 -> chunk quad, kc=1 -> 4+quad)
    const int koff0 = ((quad    ) ^ swz) * 8;
    const int koff1 = ((quad + 4) ^ swz) * 8;

    f32x4 accO[2][4];
    #pragma unroll
    for (int qb = 0; qb < 2; qb++)
        #pragma unroll
        for (int dt = 0; dt < 4; dt++) accO[qb][dt] = (f32x4){0.f, 0.f, 0.f, 0.f};
    float mi[2] = {-3.0e38f, -3.0e38f};
    float li[2] = {0.f, 0.f};

    __syncthreads();

    // QK(0) into scA (prologue)
    f32x4 scA[2][4], scB[2][4];
    {
        f32x4 kmf[4];
        #pragma unroll
        for (int nt = 0; nt < 4; nt++)
            kmf[nt] = *(const f32x4*)(mcp + nt * 16);
        bf16x8 kf[4][2];
        #pragma unroll
        for (int nt = 0; nt < 4; nt++) {
            kf[nt][0] = *(const bf16x8*)&Ks[0][(nt * 16 + l15) * 64 + koff0];
            kf[nt][1] = *(const bf16x8*)&Ks[0][(nt * 16 + l15) * 64 + koff1];
        }
        #pragma unroll
        for (int qb = 0; qb < 2; qb++)
            #pragma unroll
            for (int nt = 0; nt < 4; nt++) {
                f32x4 c = kmf[nt];
                c[0] += mq[qb]; c[1] += mq[qb]; c[2] += mq[qb]; c[3] += mq[qb];
                c = __builtin_amdgcn_mfma_f32_16x16x32_bf16(kf[nt][0], qf[qb][0], c, 0, 0, 0);
                c = __builtin_amdgcn_mfma_f32_16x16x32_bf16(kf[nt][1], qf[qb][1], c, 0, 0, 0);
                scA[qb][nt] = c;
            }
    }

    // STEP(scCur, scNxt, t): softmax+PV of tile t from scCur; QK(t+1)->scNxt.
    auto STEP = [&](f32x4 (&scCur)[2][4], f32x4 (&scNxt)[2][4], int t) {
        const int kt = t * 64;
        const int n = (t & 1) ^ 1;
        const bool hasNext = (t + 1 < ntiles);
        const int kt2 = (t + 2 < ntiles) ? (t + 2) * 64 : (ntiles - 1) * 64;

        // [A] issue global loads: V(t) frags, K(t+2) staging, masks for t+1
        bf16x8 vf[4][2];
        #pragma unroll
        for (int dt = 0; dt < 4; dt++) {
            vf[dt][0] = *(const bf16x8*)(vp[dt] + kt);
            vf[dt][1] = *(const bf16x8*)(vp[dt] + kt + 32);
        }
        uint4 k2A = *(const uint4*)&kgb[(kt2 + srow) * 64 + sch * 8];
        uint4 k2B = *(const uint4*)&kgb[(kt2 + srow) * 64 + sch * 8 + 8];
        f32x4 kmf[4];
        #pragma unroll
        for (int nt = 0; nt < 4; nt++)
            kmf[nt] = *(const f32x4*)(mcp + kt + 64 + nt * 16);

        // [F] commit K(t+1) (preloaded last iter) into Ks[n]; barrier
        *(uint4*)&Ks[n][sw0] = kstA;
        *(uint4*)&Ks[n][sw1] = kstB;
        __syncthreads();
        kstA = k2A; kstB = k2B;

        // [G] QK(t+1) into scNxt — MFMAs issue; results consumed NEXT iter,
        // so the following softmax(t) VALU overlaps their pipe latency.
        if (hasNext) {
            bf16x8 kf[4][2];
            #pragma unroll
            for (int nt = 0; nt < 4; nt++) {
                kf[nt][0] = *(const bf16x8*)&Ks[n][(nt * 16 + l15) * 64 + koff0];
                kf[nt][1] = *(const bf16x8*)&Ks[n][(nt * 16 + l15) * 64 + koff1];
            }
            #pragma unroll
            for (int qb = 0; qb < 2; qb++)
                #pragma unroll
                for (int nt = 0; nt < 4; nt++) {
                    f32x4 c = kmf[nt];
                    c[0] += mq[qb]; c[1] += mq[qb]; c[2] += mq[qb]; c[3] += mq[qb];
                    c = __builtin_amdgcn_mfma_f32_16x16x32_bf16(kf[nt][0], qf[qb][0], c, 0, 0, 0);
                    c = __builtin_amdgcn_mfma_f32_16x16x32_bf16(kf[nt][1], qf[qb][1], c, 0, 0, 0);
                    scNxt[qb][nt] = c;
                }
        }

        // [D] online softmax(t) on scCur (register-only VALU)
        #pragma unroll
        for (int qb = 0; qb < 2; qb++) {
            float mloc = fmaxf(fmaxf(scCur[qb][0][0], scCur[qb][0][1]),
                               fmaxf(scCur[qb][0][2], scCur[qb][0][3]));
            #pragma unroll
            for (int nt = 1; nt < 4; nt++)
                mloc = fmaxf(mloc, fmaxf(fmaxf(scCur[qb][nt][0], scCur[qb][nt][1]),
                                         fmaxf(scCur[qb][nt][2], scCur[qb][nt][3])));
            mloc = fmaxf(mloc, __shfl_xor(mloc, 16));
            mloc = fmaxf(mloc, __shfl_xor(mloc, 32));

            float mn = mi[qb];
            if (!__all(mloc <= mn + 4.f)) {      // defer-max: P bounded by 2^4
                float mo = mn;
                mn = fmaxf(mo, mloc);
                float alpha = __builtin_amdgcn_exp2f(mo - mn);
                li[qb] *= alpha;
                #pragma unroll
                for (int dt = 0; dt < 4; dt++) {
                    accO[qb][dt][0] *= alpha; accO[qb][dt][1] *= alpha;
                    accO[qb][dt][2] *= alpha; accO[qb][dt][3] *= alpha;
                }
                mi[qb] = mn;
            }

            float ps = 0.f;
            const int prbase = (qb * 16 + l15) * 64;
            #pragma unroll
            for (int nt = 0; nt < 4; nt++) {
                float p0 = __builtin_amdgcn_exp2f(scCur[qb][nt][0] - mn);
                float p1 = __builtin_amdgcn_exp2f(scCur[qb][nt][1] - mn);
                float p2 = __builtin_amdgcn_exp2f(scCur[qb][nt][2] - mn);
                float p3 = __builtin_amdgcn_exp2f(scCur[qb][nt][3] - mn);
                ps += (p0 + p1) + (p2 + p3);
                // keys nt*16+quad*4..+3 -> chunk 2nt+(quad>>1), sub (quad&1)*4
                uint2 pp;
                pp.x = pack_rn(p0, p1);
                pp.y = pack_rn(p2, p3);
                *(uint2*)&pw[prbase + ((2 * nt + (quad >> 1)) ^ swz) * 8 + (quad & 1) * 4] = pp;
            }
            ps += __shfl_xor(ps, 16);
            ps += __shfl_xor(ps, 32);
            li[qb] += ps;
        }

        // [E] PV(t): O^T += Vt (A) x P^T (B)
        #pragma unroll
        for (int qb = 0; qb < 2; qb++) {
            bf16x8 pf0 = *(const bf16x8*)&pw[(qb * 16 + l15) * 64 + koff0];
            bf16x8 pf1 = *(const bf16x8*)&pw[(qb * 16 + l15) * 64 + koff1];
            __builtin_amdgcn_s_setprio(1);
            #pragma unroll
            for (int dt = 0; dt < 4; dt++) {
                accO[qb][dt] = __builtin_amdgcn_mfma_f32_16x16x32_bf16(
                    vf[dt][0], pf0, accO[qb][dt], 0, 0, 0);
                accO[qb][dt] = __builtin_amdgcn_mfma_f32_16x16x32_bf16(
                    vf[dt][1], pf1, accO[qb][dt], 0, 0, 0);
            }
            __builtin_amdgcn_s_setprio(0);
        }
    };

    for (int t = 0; t < ntiles; t += 2) {
        STEP(scA, scB, t);
        if (t + 1 < ntiles) STEP(scB, scA, t + 1);
    }

    #pragma unroll
    for (int qb = 0; qb < 2; qb++) {
        float inv = 1.f / li[qb];
        int q = q0 + w * 32 + qb * 16 + l15;
        int obase = (b * 2048 + q) * 512 + h * 64 + quad * 4;
        #pragma unroll
        for (int dt = 0; dt < 4; dt++) {
            uint2 o;
            o.x = pack_rn(accO[qb][dt][0] * inv, accO[qb][dt][1] * inv);
            o.y = pack_rn(accO[qb][dt][2] * inv, accO[qb][dt][3] * inv);
            *(uint2*)&ctxB[obase + dt * 16] = o;
        }
    }
}

// ---------------------------------------------------------------------------
// Output projection — UNCHANGED from r6 (128x64 tiles, gl16 DB, counted vmcnt).
// ---------------------------------------------------------------------------
__global__ __launch_bounds__(256) void proj_out_mfma(
    const unsigned short* __restrict__ ctxB, const unsigned short* __restrict__ Wto,
    const float* __restrict__ bo, float* __restrict__ out)
{
    const int m0 = blockIdx.y * 128, n0 = blockIdx.x * 64;
    const int tid = threadIdx.x;
    const int w = tid >> 6, lane = tid & 63;
    const int l15 = lane & 15, quad = lane >> 4;
    const int wm = (w >> 1) * 64, wn = (w & 1) * 32;

    __shared__ unsigned short As[2][128 * 64];
    __shared__ unsigned short Bs[2][64 * 64];

    const int srw  = tid >> 3;
    const int csrc = (tid & 7) ^ (srw & 7);
    const unsigned short* aS[4];
    const unsigned short* bS[2];
    #pragma unroll
    for (int is = 0; is < 4; is++)
        aS[is] = Wto  + (long)(m0 + is * 32 + srw) * 512 + csrc * 8;
    #pragma unroll
    for (int is = 0; is < 2; is++)
        bS[is] = ctxB + (long)(n0 + is * 32 + srw) * 512 + csrc * 8;

    const int koff0 = ((quad    ) ^ (l15 & 7)) * 8;
    const int koff1 = ((quad + 4) ^ (l15 & 7)) * 8;

    f32x4 acc[4][2];
    #pragma unroll
    for (int i = 0; i < 4; i++)
        #pragma unroll
        for (int j = 0; j < 2; j++) acc[i][j] = (f32x4){0.f, 0.f, 0.f, 0.f};

    #define STAGE_O(buf, k0)                                        \
        do {                                                        \
            _Pragma("unroll")                                       \
            for (int is = 0; is < 4; is++)                          \
                gl16(aS[is] + (k0), &As[buf][is * 2048 + w * 512]); \
            _Pragma("unroll")                                       \
            for (int is = 0; is < 2; is++)                          \
                gl16(bS[is] + (k0), &Bs[buf][is * 2048 + w * 512]); \
        } while (0)

    STAGE_O(0, 0);
    for (int k = 0; k < 8; k++) {
        const int cur = k & 1;
        if (k < 7) {
            STAGE_O(cur ^ 1, (k + 1) * 64);
            asm volatile("s_waitcnt vmcnt(6)" ::: "memory");
        } else {
            asm volatile("s_waitcnt vmcnt(0)" ::: "memory");
        }
        asm volatile("s_barrier" ::: "memory");
        #pragma unroll
        for (int kc = 0; kc < 2; kc++) {
            const int ko = kc ? koff1 : koff0;
            bf16x8 a[4], bb[2];
            #pragma unroll
            for (int i = 0; i < 4; i++)
                a[i] = *(const bf16x8*)&As[cur][(wm + 16 * i + l15) * 64 + ko];
            #pragma unroll
            for (int j = 0; j < 2; j++)
                bb[j] = *(const bf16x8*)&Bs[cur][(wn + 16 * j + l15) * 64 + ko];
            #pragma unroll
            for (int i = 0; i < 4; i++)
                #pragma unroll
                for (int j = 0; j < 2; j++)
                    acc[i][j] = __builtin_amdgcn_mfma_f32_16x16x32_bf16(a[i], bb[j], acc[i][j], 0, 0, 0);
        }
        asm volatile("s_barrier" ::: "memory");
    }
    #undef STAGE_O

    #pragma unroll
    for (int j = 0; j < 2; j++) {
        int sg = n0 + wn + 16 * j + l15;
        #pragma unroll
        for (int i = 0; i < 4; i++) {
            int F = m0 + wm + 16 * i + quad * 4;
            float4 b4 = *(const float4*)&bo[F];
            float4 vv;
            vv.x = acc[i][j][0] + b4.x;
            vv.y = acc[i][j][1] + b4.y;
            vv.z = acc[i][j][2] + b4.z;
            vv.w = acc[i][j][3] + b4.w;
            *(float4*)&out[sg * 512 + F] = vv;
        }
    }
}

extern "C" void kernel_launch(void* const* d_in, const int* in_sizes, int n_in,
                              void* d_out, int out_size, void* d_ws, size_t ws_size,
                              hipStream_t stream)
{
    const float* query = (const float*)d_in[0];
    const float* value = (const float*)d_in[1];
    const int*   amask = (const int*)d_in[2];
    const float* Wq = (const float*)d_in[3];
    const float* bq = (const float*)d_in[4];
    const float* Wk = (const float*)d_in[5];
    const float* bk = (const float*)d_in[6];
    const float* Wv = (const float*)d_in[7];
    const float* bv = (const float*)d_in[8];
    const float* Wo = (const float*)d_in[9];
    const float* bo = (const float*)d_in[10];
    float* out = (float*)d_out;

    char* ws = (char*)d_ws;
    const size_t MB = 1 << 20;
    const size_t KB = 1 << 10;
    unsigned short* Xbq = (unsigned short*)(ws);                  // 8 MB bf16
    unsigned short* Xbv = (unsigned short*)(ws + 8 * MB);         // 8 MB
    unsigned short* Wtq = (unsigned short*)(ws + 16 * MB);        // 0.5 MB each
    unsigned short* Wtk = (unsigned short*)(ws + 16 * MB + MB / 2);
    unsigned short* Wtv = (unsigned short*)(ws + 17 * MB);
    unsigned short* Wto = (unsigned short*)(ws + 17 * MB + MB / 2);
    unsigned short* Qb  = (unsigned short*)(ws + 18 * MB);        // 8 MB (bh,s,d)
    unsigned short* Kb  = (unsigned short*)(ws + 26 * MB);        // 8 MB (bh,i,d) compacted
    unsigned short* VtG = (unsigned short*)(ws + 34 * MB);        // 8 MB (bh,d,i) compacted
    // aux region (42MB+): idx/masks — never aliased with anything.
    int*   idx1 = (int*)(ws + 42 * MB);                           // 32 KB
    float* Mf   = (float*)(ws + 42 * MB + 32 * KB);               // 32 KB
    float* Mc   = (float*)(ws + 42 * MB + 64 * KB);               // 32 KB
    int*   nv   = (int*)(ws + 42 * MB + 96 * KB);                 // 16 B
    // ctx reuses the Xbq region (dead after proj_qkv; flash writes it,
    // proj_out reads it — strictly stream-ordered).
    unsigned short* ctx = Xbq;                                    // 8 MB (b*s, h*d)

    pre_all<<<dim3(4353), 256, 0, stream>>>(query, value, amask,
                                            Wq, Wk, Wv, Wo,
                                            Xbq, Xbv, Wtq, Wtk, Wtv, Wto,
                                            idx1, nv, Mf, Mc);
    proj_qkv_mfma<<<dim3(128, 4, 3), 256, 0, stream>>>(Xbq, Xbv, Wtq, Wtk, Wtv,
                                                       bq, bk, bv, idx1, nv,
                                                       Qb, Kb, VtG);
    flash_mfma<<<dim3(512), 256, 0, stream>>>(Qb, Kb, VtG, Mf, Mc, nv, ctx);
    proj_out_mfma<<<dim3(128, 4), 256, 0, stream>>>(ctx, Wto, bo, out);
}